// Round 7
// baseline (394.007 us; speedup 1.0000x reference)
//
#include <hip/hip_runtime.h>
#include <stdint.h>

// GATConv: N=100000 nodes, E=1600000 edges, IN=128, HEADS=4, OUT=32 (HO=128)
// fp32 tensors; edge_index int32.
//
// R7: (1) per-edge head weights computed in bucketB (coalesced planar wts[4][E])
// so gather's inner loop is pure load+FMA (R6 gather was 70% VALU on redundant
// exp/leaky); (2) gemm rewritten: W-only LDS (2 blocks/CU), x read from global
// via wave-broadcast, 8x4 register tile -> FMA-bound.

#define NN 100000
#define EE 1600000
#define INCH 128
#define HO 128           // HEADS*OUT
#define HEADS 4
#define OUTC 32

#define SCAN_BLOCKS 250  // 250 * 400 = 100000

#define BSH 8                             // 256 nodes per bucket
#define NBUCK ((NN + 255) >> BSH)         // 391
#define CHA 8192                          // edges per bucketA block
#define ABLK ((EE + CHA - 1) / CHA)       // 196
#define CAPB 8192                         // bucketB LDS record capacity

typedef unsigned short ushort_t;
typedef unsigned int uint_t;

__device__ __forceinline__ float bfl(uint_t u) { return __uint_as_float(u << 16); }
__device__ __forceinline__ float bfh(uint_t u) { return __uint_as_float(u & 0xffff0000u); }
__device__ __forceinline__ uint_t f2bf(float f) {
    uint_t u = __float_as_uint(f);
    u = (u + 0x7fffu + ((u >> 16) & 1u)) >> 16;   // round-to-nearest-even
    return u;
}

// ---------------- GEMM + fused attention-score epilogue
// 64 rows x 128 cols per block; thread = 8 rows x 4 cols. W in LDS (64KB),
// x read from global (32 col-lanes broadcast the same row -> L1).
__global__ __launch_bounds__(256) void gemm_h(const float* __restrict__ x,
                                              const float* __restrict__ W,
                                              const float* __restrict__ att,
                                              ushort_t* __restrict__ hb,
                                              float* __restrict__ s_src,
                                              float* __restrict__ s_tgt) {
    __shared__ __align__(16) float wsm[128 * 128];   // 64 KB
    const int tid = threadIdx.x;

    const float4* W4 = (const float4*)W;
    float4* w4 = (float4*)wsm;
#pragma unroll
    for (int i = 0; i < 16; ++i) w4[tid + 256 * i] = W4[tid + 256 * i];

    const int rg = tid >> 5, cg = tid & 31;
    const int row0 = blockIdx.x * 64 + rg * 8;
    const int c0 = cg * 4;
    const int hd = cg >> 3;
    const int co = c0 & 31;
    const float4 as = *(const float4*)(att + hd * 64 + co);
    const float4 at = *(const float4*)(att + hd * 64 + 32 + co);

    const float* xp[8];
#pragma unroll
    for (int i = 0; i < 8; ++i) {
        int r = row0 + i;
        if (r >= NN) r = NN - 1;          // clamp; stores guarded below
        xp[i] = x + (size_t)r * INCH;
    }
    __syncthreads();

    float acc[8][4] = {};
#pragma unroll 2
    for (int kb = 0; kb < 32; ++kb) {
        float4 xr[8];
#pragma unroll
        for (int i = 0; i < 8; ++i) xr[i] = *(const float4*)(xp[i] + kb * 4);
#pragma unroll
        for (int j = 0; j < 4; ++j) {
            const float4 wv = *(const float4*)(wsm + (kb * 4 + j) * 128 + c0);
#pragma unroll
            for (int i = 0; i < 8; ++i) {
                const float xv = (j == 0) ? xr[i].x : (j == 1) ? xr[i].y
                               : (j == 2) ? xr[i].z : xr[i].w;
                acc[i][0] = fmaf(xv, wv.x, acc[i][0]);
                acc[i][1] = fmaf(xv, wv.y, acc[i][1]);
                acc[i][2] = fmaf(xv, wv.z, acc[i][2]);
                acc[i][3] = fmaf(xv, wv.w, acc[i][3]);
            }
        }
    }
    // h write (bf16), guarded
#pragma unroll
    for (int i = 0; i < 8; ++i) {
        const int r = row0 + i;
        if (r < NN) {
            uint2 st2;
            st2.x = f2bf(acc[i][0]) | (f2bf(acc[i][1]) << 16);
            st2.y = f2bf(acc[i][2]) | (f2bf(acc[i][3]) << 16);
            *(uint2*)(hb + (size_t)r * HO + c0) = st2;
        }
    }
    // fused s epilogue: per-row partial dots, reduce across 8 lanes of the head
    float ssp[8], stp[8];
#pragma unroll
    for (int i = 0; i < 8; ++i) {
        ssp[i] = acc[i][0] * as.x + acc[i][1] * as.y + acc[i][2] * as.z + acc[i][3] * as.w;
        stp[i] = acc[i][0] * at.x + acc[i][1] * at.y + acc[i][2] * at.z + acc[i][3] * at.w;
    }
#pragma unroll
    for (int d = 1; d < 8; d <<= 1) {
#pragma unroll
        for (int i = 0; i < 8; ++i) {
            ssp[i] += __shfl_xor(ssp[i], d, 64);
            stp[i] += __shfl_xor(stp[i], d, 64);
        }
    }
    if ((cg & 7) == 0) {
#pragma unroll
        for (int i = 0; i < 8; ++i) {
            const int r = row0 + i;
            if (r < NN) {
                s_src[r * 4 + hd] = ssp[i];
                s_tgt[r * 4 + hd] = stp[i];
            }
        }
    }
}

// ---------------- histogram of tgt degrees
__global__ __launch_bounds__(256) void hist_k(const int* __restrict__ ei,
                                              int* __restrict__ deg) {
    const int e = blockIdx.x * 256 + threadIdx.x;
    if (e < EE) atomicAdd(deg + ei[EE + e], 1);
}

// ---------------- scan pass 1: per-block chunk sums
__global__ __launch_bounds__(256) void blocksum_k(const int* __restrict__ deg,
                                                  int* __restrict__ blockSums) {
    __shared__ int red[256];
    const int t = threadIdx.x;
    const int i2 = blockIdx.x * 200 + t;     // int2 index, 200 per block
    int s = 0;
    if (t < 200) {
        const int2 d = ((const int2*)deg)[i2];
        s = d.x + d.y;
    }
    red[t] = s;
    __syncthreads();
#pragma unroll
    for (int off = 128; off > 0; off >>= 1) {
        if (t < off) red[t] += red[t + off];
        __syncthreads();
    }
    if (t == 0) blockSums[blockIdx.x] = red[0];
}

// ---------------- scan pass 2: exclusive scan of 250 block sums
__global__ __launch_bounds__(256) void scansums_k(const int* __restrict__ blockSums,
                                                  int* __restrict__ blockOffs,
                                                  int* __restrict__ offs) {
    __shared__ int p[256];
    const int t = threadIdx.x;
    int v = (t < SCAN_BLOCKS) ? blockSums[t] : 0;
    p[t] = v;
    __syncthreads();
#pragma unroll
    for (int off = 1; off < 256; off <<= 1) {
        int u = (t >= off) ? p[t - off] : 0;
        __syncthreads();
        p[t] += u;
        __syncthreads();
    }
    if (t < SCAN_BLOCKS) blockOffs[t] = p[t] - v;   // exclusive
    if (t == 0) offs[NN] = EE;
}

// ---------------- scan pass 3: apply — write offs & per-bucket cursors
__global__ __launch_bounds__(256) void scanapply_k(const int* __restrict__ deg,
                                                   const int* __restrict__ blockOffs,
                                                   int* __restrict__ offs,
                                                   int* __restrict__ gcur) {
    __shared__ int p[256];
    const int t = threadIdx.x;
    const int i2 = blockIdx.x * 200 + t;
    int2 d = make_int2(0, 0);
    if (t < 200) d = ((const int2*)deg)[i2];
    const int s = d.x + d.y;
    p[t] = s;
    __syncthreads();
#pragma unroll
    for (int off = 1; off < 256; off <<= 1) {
        int u = (t >= off) ? p[t - off] : 0;
        __syncthreads();
        p[t] += u;
        __syncthreads();
    }
    if (t < 200) {
        const int run = blockOffs[blockIdx.x] + p[t] - s;   // exclusive prefix
        const int2 o = make_int2(run, run + d.x);
        ((int2*)offs)[i2] = o;
        const int node = i2 * 2;
        if ((node & 255) == 0) gcur[node >> BSH] = run;     // bucket cursor seed
    }
}

// ---------------- bucket pass A: LDS-binned scatter into bucket regions
__global__ __launch_bounds__(256) void bucketA_k(const int* __restrict__ ei,
                                                 int* __restrict__ gcur,
                                                 uint_t* __restrict__ grec) {
    __shared__ int hist[NBUCK];
    __shared__ int lofs[NBUCK + 1];
    __shared__ int lcur[NBUCK];
    __shared__ int gbase[NBUCK];
    __shared__ int sc[256];
    __shared__ uint_t stag[CHA];        // 32 KB
    const int tid = threadIdx.x;
    const int e0 = blockIdx.x * CHA;
    const int cnt = min(CHA, EE - e0);

    for (int b = tid; b < NBUCK; b += 256) hist[b] = 0;
    __syncthreads();
    for (int i = tid; i < cnt; i += 256)
        atomicAdd(&hist[ei[EE + e0 + i] >> BSH], 1);
    __syncthreads();
    const int b0 = 2 * tid, b1 = 2 * tid + 1;
    const int h0 = (b0 < NBUCK) ? hist[b0] : 0;
    const int h1 = (b1 < NBUCK) ? hist[b1] : 0;
    sc[tid] = h0 + h1;
    __syncthreads();
#pragma unroll
    for (int off = 1; off < 256; off <<= 1) {
        int u = (tid >= off) ? sc[tid - off] : 0;
        __syncthreads();
        sc[tid] += u;
        __syncthreads();
    }
    const int ex = sc[tid] - (h0 + h1);
    if (b0 < NBUCK) { lofs[b0] = ex;      lcur[b0] = ex; }
    if (b1 < NBUCK) { lofs[b1] = ex + h0; lcur[b1] = ex + h0; }
    if (tid == 0) lofs[NBUCK] = cnt;
    __syncthreads();
    for (int b = tid; b < NBUCK; b += 256) gbase[b] = atomicAdd(&gcur[b], hist[b]);
    for (int i = tid; i < cnt; i += 256) {
        const int src = ei[e0 + i];
        const int tgt = ei[EE + e0 + i];
        const int b = tgt >> BSH;
        const int p = atomicAdd(&lcur[b], 1);
        stag[p] = (uint_t)src | ((uint_t)(tgt & 255) << 17);   // src<2^17
    }
    __syncthreads();
    for (int i = tid; i < cnt; i += 256) {
        int lo = 0, hi = NBUCK - 1;
        while (lo < hi) {
            const int mid = (lo + hi + 1) >> 1;
            if (lofs[mid] <= i) lo = mid; else hi = mid - 1;
        }
        grec[gbase[lo] + (i - lofs[lo])] = stag[i];
    }
}

// ---------------- bucket pass B: per-bucket LDS counting sort -> sorted_src + planar wts
__global__ __launch_bounds__(256) void bucketB_k(const int* __restrict__ offs,
                                                 const uint_t* __restrict__ grec,
                                                 const float* __restrict__ s_src,
                                                 const float* __restrict__ s_tgt,
                                                 int* __restrict__ sorted_src,
                                                 float* __restrict__ wts) {
    __shared__ int cur[256];
    __shared__ uint_t sbuf[CAPB];       // 32 KB
    const int tid = threadIdx.x;
    const int n0 = blockIdx.x << BSH;
    const int nn = min(256, NN - n0);
    const int R0 = offs[n0];
    const int R1 = offs[min(n0 + 256, NN)];
    const int cnt = R1 - R0;
    if (tid < nn) cur[tid] = offs[n0 + tid] - R0;
    __syncthreads();
    if (cnt <= CAPB) {
        for (int i = tid; i < cnt; i += 256) {
            const uint_t r = grec[R0 + i];
            const int p = atomicAdd(&cur[r >> 17], 1);
            sbuf[p] = r;
        }
        __syncthreads();
        for (int i = tid; i < cnt; i += 256) {
            const uint_t r = sbuf[i];
            const int s = (int)(r & 0x1FFFF);
            const int n = n0 + (int)(r >> 17);
            const float4 a = *(const float4*)(s_src + (size_t)s * 4);
            const float4 b = *(const float4*)(s_tgt + (size_t)n * 4);
            const float sc0 = a.x + b.x, sc1 = a.y + b.y, sc2 = a.z + b.z, sc3 = a.w + b.w;
            sorted_src[R0 + i] = s;
            wts[0 * (size_t)EE + R0 + i] = __expf(-(sc0 > 0.f ? sc0 : 0.2f * sc0));
            wts[1 * (size_t)EE + R0 + i] = __expf(-(sc1 > 0.f ? sc1 : 0.2f * sc1));
            wts[2 * (size_t)EE + R0 + i] = __expf(-(sc2 > 0.f ? sc2 : 0.2f * sc2));
            wts[3 * (size_t)EE + R0 + i] = __expf(-(sc3 > 0.f ? sc3 : 0.2f * sc3));
        }
    } else {   // statistically unreachable fallback (>= 64 sigma)
        for (int i = tid; i < cnt; i += 256) {
            const uint_t r = grec[R0 + i];
            const int p = atomicAdd(&cur[r >> 17], 1);
            const int s = (int)(r & 0x1FFFF);
            const int n = n0 + (int)(r >> 17);
            const float4 a = *(const float4*)(s_src + (size_t)s * 4);
            const float4 b = *(const float4*)(s_tgt + (size_t)n * 4);
            const float sc0 = a.x + b.x, sc1 = a.y + b.y, sc2 = a.z + b.z, sc3 = a.w + b.w;
            sorted_src[R0 + p] = s;
            wts[0 * (size_t)EE + R0 + p] = __expf(-(sc0 > 0.f ? sc0 : 0.2f * sc0));
            wts[1 * (size_t)EE + R0 + p] = __expf(-(sc1 > 0.f ? sc1 : 0.2f * sc1));
            wts[2 * (size_t)EE + R0 + p] = __expf(-(sc2 > 0.f ? sc2 : 0.2f * sc2));
            wts[3 * (size_t)EE + R0 + p] = __expf(-(sc3 > 0.f ? sc3 : 0.2f * sc3));
        }
    }
}

// ---------------- gather: one wave per node, pure load+FMA inner loop
__global__ __launch_bounds__(256) void gather_k(const int* __restrict__ offs,
                                                const int* __restrict__ sorted_src,
                                                const float* __restrict__ wts,
                                                const ushort_t* __restrict__ hb,
                                                const float* __restrict__ bias,
                                                float* __restrict__ out) {
    const int n = blockIdx.x * 4 + (threadIdx.x >> 6);
    const int l = threadIdx.x & 63;
    const int c0 = l * 2;              // two channels per lane (same head)
    const int hd = l >> 4;
    const int p0 = offs[n], p1 = offs[n + 1];
    const float* wp = wts + (size_t)hd * EE;
    float ax = 0.f, ay = 0.f, wsum = 0.f;
    int p = p0;
    // peel to 16B alignment for uint4/float4 loads
    const int pre = min((4 - (p0 & 3)) & 3, p1 - p0);
    for (int q = 0; q < pre; ++q, ++p) {
        const int s0 = sorted_src[p];
        const float w0 = wp[p];
        const uint_t v0 = *(const uint_t*)(hb + (size_t)s0 * HO + c0);
        ax = fmaf(w0, bfl(v0), ax); ay = fmaf(w0, bfh(v0), ay);
        wsum += w0;
    }
    for (; p + 3 < p1; p += 4) {
        const uint4 s4 = *(const uint4*)(sorted_src + p);
        const float4 wv = *(const float4*)(wp + p);
        const uint_t v0 = *(const uint_t*)(hb + (size_t)s4.x * HO + c0);
        const uint_t v1 = *(const uint_t*)(hb + (size_t)s4.y * HO + c0);
        const uint_t v2 = *(const uint_t*)(hb + (size_t)s4.z * HO + c0);
        const uint_t v3 = *(const uint_t*)(hb + (size_t)s4.w * HO + c0);
        ax = fmaf(wv.x, bfl(v0), ax); ay = fmaf(wv.x, bfh(v0), ay);
        ax = fmaf(wv.y, bfl(v1), ax); ay = fmaf(wv.y, bfh(v1), ay);
        ax = fmaf(wv.z, bfl(v2), ax); ay = fmaf(wv.z, bfh(v2), ay);
        ax = fmaf(wv.w, bfl(v3), ax); ay = fmaf(wv.w, bfh(v3), ay);
        wsum += (wv.x + wv.y) + (wv.z + wv.w);
    }
    for (; p < p1; ++p) {
        const int s0 = sorted_src[p];
        const float w0 = wp[p];
        const uint_t v0 = *(const uint_t*)(hb + (size_t)s0 * HO + c0);
        ax = fmaf(w0, bfl(v0), ax); ay = fmaf(w0, bfh(v0), ay);
        wsum += w0;
    }
    const float inv = 1.f / fmaxf(wsum, 1e-10f);
    float2 o;
    o.x = ax * inv + bias[c0];
    o.y = ay * inv + bias[c0 + 1];
    *(float2*)(out + (size_t)n * HO + c0) = o;
}

extern "C" void kernel_launch(void* const* d_in, const int* in_sizes, int n_in,
                              void* d_out, int out_size, void* d_ws, size_t ws_size,
                              hipStream_t stream) {
    const float* x    = (const float*)d_in[0];
    const int*   ei   = (const int*)d_in[1];
    const float* W    = (const float*)d_in[2];
    const float* att  = (const float*)d_in[3];
    const float* bias = (const float*)d_in[4];
    float* out = (float*)d_out;

    char* ws = (char*)d_ws;
    const size_t HB_B  = (size_t)NN * HO * 2;        // 25.6 MB (bf16 h)
    const size_t SS_B  = (size_t)EE * 4;             // 6.4 MB
    const size_t GR_B  = (size_t)EE * 4;             // 6.4 MB (packed records)
    const size_t WT_B  = (size_t)EE * 4 * HEADS;     // 25.6 MB (planar wts)
    const size_t S_B   = (size_t)NN * HEADS * 4;     // 1.6 MB
    const size_t DEG_B = (size_t)NN * 4;             // 400 KB
    const size_t OFF_B = ((size_t)(NN + 1) * 4 + 15) & ~15ull;
    const size_t BS_B  = 256 * 4;
    const size_t GC_B  = ((size_t)NBUCK * 4 + 15) & ~15ull;

    size_t o = 0;
    ushort_t* hb         = (ushort_t*)(ws + o); o += HB_B;
    int*      sorted_src = (int*)(ws + o); o += SS_B;
    uint_t*   grec       = (uint_t*)(ws + o); o += GR_B;
    float*    wts        = (float*)(ws + o); o += WT_B;
    float*    ssrc       = (float*)(ws + o); o += S_B;
    float*    stgt       = (float*)(ws + o); o += S_B;
    int*      deg        = (int*)(ws + o); o += DEG_B;
    int*      offs       = (int*)(ws + o); o += OFF_B;
    int*      gcur       = (int*)(ws + o); o += GC_B;
    int*      blockSums  = (int*)(ws + o); o += BS_B;
    int*      blockOffs  = (int*)(ws + o); o += BS_B;

    hipMemsetAsync(deg, 0, DEG_B, stream);

    gemm_h<<<(NN + 63) / 64, 256, 0, stream>>>(x, W, att, hb, ssrc, stgt);  // 1563 blocks
    hist_k<<<(EE + 255) / 256, 256, 0, stream>>>(ei, deg);                  // 6250 blocks
    blocksum_k<<<SCAN_BLOCKS, 256, 0, stream>>>(deg, blockSums);
    scansums_k<<<1, 256, 0, stream>>>(blockSums, blockOffs, offs);
    scanapply_k<<<SCAN_BLOCKS, 256, 0, stream>>>(deg, blockOffs, offs, gcur);
    bucketA_k<<<ABLK, 256, 0, stream>>>(ei, gcur, grec);                    // 196 blocks
    bucketB_k<<<NBUCK, 256, 0, stream>>>(offs, grec, ssrc, stgt,
                                         sorted_src, wts);                  // 391 blocks
    gather_k<<<NN / 4, 256, 0, stream>>>(offs, sorted_src, wts,
                                         hb, bias, out);                    // 25000 blocks
}

// Round 8
// 378.418 us; speedup vs baseline: 1.0412x; 1.0412x over previous
//
#include <hip/hip_runtime.h>
#include <stdint.h>

// GATConv: N=100000 nodes, E=1600000 edges, IN=128, HEADS=4, OUT=32 (HO=128)
// fp32 tensors; edge_index int32.
//
// R8: gemm reverted to dual-LDS-operand form with b128 reads on BOTH x and W
// (R7's x-from-global was latency-bound at 17% occupancy: 90us; R5/R6's scalar
// ds_read_b32 x was LDS-issue-bound). 4-k inner blocks: 8 ds_read_b128 per
// 64 FMA -> FMA-bound. Rest of pipeline identical to R7.

#define NN 100000
#define EE 1600000
#define INCH 128
#define HO 128           // HEADS*OUT
#define HEADS 4
#define OUTC 32

#define SCAN_BLOCKS 250  // 250 * 400 = 100000

#define BSH 8                             // 256 nodes per bucket
#define NBUCK ((NN + 255) >> BSH)         // 391
#define CHA 8192                          // edges per bucketA block
#define ABLK ((EE + CHA - 1) / CHA)       // 196
#define CAPB 8192                         // bucketB LDS record capacity

typedef unsigned short ushort_t;
typedef unsigned int uint_t;

__device__ __forceinline__ float bfl(uint_t u) { return __uint_as_float(u << 16); }
__device__ __forceinline__ float bfh(uint_t u) { return __uint_as_float(u & 0xffff0000u); }
__device__ __forceinline__ uint_t f2bf(float f) {
    uint_t u = __float_as_uint(f);
    u = (u + 0x7fffu + ((u >> 16) & 1u)) >> 16;   // round-to-nearest-even
    return u;
}

// ---------------- GEMM + fused attention-score epilogue
// 32 rows x 128 cols per block of 256 threads; thread = 4 rows x 4 cols.
// W (64KB) + x tile (16KB) in LDS; inner loop over 4-k blocks with
// ds_read_b128 on both operands: 8 b128 per 64 FMA -> FMA-bound.
__global__ __launch_bounds__(256) void gemm_h(const float* __restrict__ x,
                                              const float* __restrict__ W,
                                              const float* __restrict__ att,
                                              ushort_t* __restrict__ hb,
                                              float* __restrict__ s_src,
                                              float* __restrict__ s_tgt) {
    __shared__ __align__(16) float wsm[128 * 128];   // 64 KB
    __shared__ __align__(16) float xs[32 * 128];     // 16 KB
    const int tid = threadIdx.x;
    const int row0 = blockIdx.x * 32;

    const float4* W4 = (const float4*)W;
    float4* w4 = (float4*)wsm;
#pragma unroll
    for (int i = 0; i < 16; ++i) w4[tid + 256 * i] = W4[tid + 256 * i];

    const float4* x4 = (const float4*)(x + (size_t)row0 * INCH);
    float4* xs4 = (float4*)xs;
#pragma unroll
    for (int i = 0; i < 4; ++i) xs4[tid + 256 * i] = x4[tid + 256 * i];

    const int rg = tid >> 5, cg = tid & 31;
    const int r0 = rg * 4, c0 = cg * 4;
    const int hd = cg >> 3;            // head of this thread's 4 columns
    const int co = c0 & 31;            // offset within head
    const float4 as = *(const float4*)(att + hd * 64 + co);
    const float4 at = *(const float4*)(att + hd * 64 + 32 + co);
    __syncthreads();

    float acc[4][4] = {};
#pragma unroll 4
    for (int kb = 0; kb < 32; ++kb) {
        float4 xv[4];
#pragma unroll
        for (int i = 0; i < 4; ++i)
            xv[i] = *(const float4*)(xs + (r0 + i) * 128 + kb * 4);   // b128, broadcast
#pragma unroll
        for (int j = 0; j < 4; ++j) {
            const float4 wv = *(const float4*)(wsm + (kb * 4 + j) * 128 + c0);  // b128
#pragma unroll
            for (int i = 0; i < 4; ++i) {
                const float xvj = (j == 0) ? xv[i].x : (j == 1) ? xv[i].y
                                : (j == 2) ? xv[i].z : xv[i].w;
                acc[i][0] = fmaf(xvj, wv.x, acc[i][0]);
                acc[i][1] = fmaf(xvj, wv.y, acc[i][1]);
                acc[i][2] = fmaf(xvj, wv.z, acc[i][2]);
                acc[i][3] = fmaf(xvj, wv.w, acc[i][3]);
            }
        }
    }
    // h write (bf16)
#pragma unroll
    for (int i = 0; i < 4; ++i) {
        uint2 st2;
        st2.x = f2bf(acc[i][0]) | (f2bf(acc[i][1]) << 16);
        st2.y = f2bf(acc[i][2]) | (f2bf(acc[i][3]) << 16);
        *(uint2*)(hb + (size_t)(row0 + r0 + i) * HO + c0) = st2;
    }
    // fused s epilogue: per-row partial dots, reduce across the 8 lanes of this head
    float ssp[4], stp[4];
#pragma unroll
    for (int i = 0; i < 4; ++i) {
        ssp[i] = acc[i][0] * as.x + acc[i][1] * as.y + acc[i][2] * as.z + acc[i][3] * as.w;
        stp[i] = acc[i][0] * at.x + acc[i][1] * at.y + acc[i][2] * at.z + acc[i][3] * at.w;
    }
#pragma unroll
    for (int d = 1; d < 8; d <<= 1) {
#pragma unroll
        for (int i = 0; i < 4; ++i) {
            ssp[i] += __shfl_xor(ssp[i], d, 64);
            stp[i] += __shfl_xor(stp[i], d, 64);
        }
    }
    if ((cg & 7) == 0) {
#pragma unroll
        for (int i = 0; i < 4; ++i) {
            const int row = row0 + r0 + i;
            s_src[row * 4 + hd] = ssp[i];
            s_tgt[row * 4 + hd] = stp[i];
        }
    }
}

// ---------------- histogram of tgt degrees
__global__ __launch_bounds__(256) void hist_k(const int* __restrict__ ei,
                                              int* __restrict__ deg) {
    const int e = blockIdx.x * 256 + threadIdx.x;
    if (e < EE) atomicAdd(deg + ei[EE + e], 1);
}

// ---------------- scan pass 1: per-block chunk sums
__global__ __launch_bounds__(256) void blocksum_k(const int* __restrict__ deg,
                                                  int* __restrict__ blockSums) {
    __shared__ int red[256];
    const int t = threadIdx.x;
    const int i2 = blockIdx.x * 200 + t;     // int2 index, 200 per block
    int s = 0;
    if (t < 200) {
        const int2 d = ((const int2*)deg)[i2];
        s = d.x + d.y;
    }
    red[t] = s;
    __syncthreads();
#pragma unroll
    for (int off = 128; off > 0; off >>= 1) {
        if (t < off) red[t] += red[t + off];
        __syncthreads();
    }
    if (t == 0) blockSums[blockIdx.x] = red[0];
}

// ---------------- scan pass 2: exclusive scan of 250 block sums
__global__ __launch_bounds__(256) void scansums_k(const int* __restrict__ blockSums,
                                                  int* __restrict__ blockOffs,
                                                  int* __restrict__ offs) {
    __shared__ int p[256];
    const int t = threadIdx.x;
    int v = (t < SCAN_BLOCKS) ? blockSums[t] : 0;
    p[t] = v;
    __syncthreads();
#pragma unroll
    for (int off = 1; off < 256; off <<= 1) {
        int u = (t >= off) ? p[t - off] : 0;
        __syncthreads();
        p[t] += u;
        __syncthreads();
    }
    if (t < SCAN_BLOCKS) blockOffs[t] = p[t] - v;   // exclusive
    if (t == 0) offs[NN] = EE;
}

// ---------------- scan pass 3: apply — write offs & per-bucket cursors
__global__ __launch_bounds__(256) void scanapply_k(const int* __restrict__ deg,
                                                   const int* __restrict__ blockOffs,
                                                   int* __restrict__ offs,
                                                   int* __restrict__ gcur) {
    __shared__ int p[256];
    const int t = threadIdx.x;
    const int i2 = blockIdx.x * 200 + t;
    int2 d = make_int2(0, 0);
    if (t < 200) d = ((const int2*)deg)[i2];
    const int s = d.x + d.y;
    p[t] = s;
    __syncthreads();
#pragma unroll
    for (int off = 1; off < 256; off <<= 1) {
        int u = (t >= off) ? p[t - off] : 0;
        __syncthreads();
        p[t] += u;
        __syncthreads();
    }
    if (t < 200) {
        const int run = blockOffs[blockIdx.x] + p[t] - s;   // exclusive prefix
        const int2 o = make_int2(run, run + d.x);
        ((int2*)offs)[i2] = o;
        const int node = i2 * 2;
        if ((node & 255) == 0) gcur[node >> BSH] = run;     // bucket cursor seed
    }
}

// ---------------- bucket pass A: LDS-binned scatter into bucket regions
__global__ __launch_bounds__(256) void bucketA_k(const int* __restrict__ ei,
                                                 int* __restrict__ gcur,
                                                 uint_t* __restrict__ grec) {
    __shared__ int hist[NBUCK];
    __shared__ int lofs[NBUCK + 1];
    __shared__ int lcur[NBUCK];
    __shared__ int gbase[NBUCK];
    __shared__ int sc[256];
    __shared__ uint_t stag[CHA];        // 32 KB
    const int tid = threadIdx.x;
    const int e0 = blockIdx.x * CHA;
    const int cnt = min(CHA, EE - e0);

    for (int b = tid; b < NBUCK; b += 256) hist[b] = 0;
    __syncthreads();
    for (int i = tid; i < cnt; i += 256)
        atomicAdd(&hist[ei[EE + e0 + i] >> BSH], 1);
    __syncthreads();
    const int b0 = 2 * tid, b1 = 2 * tid + 1;
    const int h0 = (b0 < NBUCK) ? hist[b0] : 0;
    const int h1 = (b1 < NBUCK) ? hist[b1] : 0;
    sc[tid] = h0 + h1;
    __syncthreads();
#pragma unroll
    for (int off = 1; off < 256; off <<= 1) {
        int u = (tid >= off) ? sc[tid - off] : 0;
        __syncthreads();
        sc[tid] += u;
        __syncthreads();
    }
    const int ex = sc[tid] - (h0 + h1);
    if (b0 < NBUCK) { lofs[b0] = ex;      lcur[b0] = ex; }
    if (b1 < NBUCK) { lofs[b1] = ex + h0; lcur[b1] = ex + h0; }
    if (tid == 0) lofs[NBUCK] = cnt;
    __syncthreads();
    for (int b = tid; b < NBUCK; b += 256) gbase[b] = atomicAdd(&gcur[b], hist[b]);
    for (int i = tid; i < cnt; i += 256) {
        const int src = ei[e0 + i];
        const int tgt = ei[EE + e0 + i];
        const int b = tgt >> BSH;
        const int p = atomicAdd(&lcur[b], 1);
        stag[p] = (uint_t)src | ((uint_t)(tgt & 255) << 17);   // src<2^17
    }
    __syncthreads();
    for (int i = tid; i < cnt; i += 256) {
        int lo = 0, hi = NBUCK - 1;
        while (lo < hi) {
            const int mid = (lo + hi + 1) >> 1;
            if (lofs[mid] <= i) lo = mid; else hi = mid - 1;
        }
        grec[gbase[lo] + (i - lofs[lo])] = stag[i];
    }
}

// ---------------- bucket pass B: per-bucket LDS counting sort -> sorted_src + planar wts
__global__ __launch_bounds__(256) void bucketB_k(const int* __restrict__ offs,
                                                 const uint_t* __restrict__ grec,
                                                 const float* __restrict__ s_src,
                                                 const float* __restrict__ s_tgt,
                                                 int* __restrict__ sorted_src,
                                                 float* __restrict__ wts) {
    __shared__ int cur[256];
    __shared__ uint_t sbuf[CAPB];       // 32 KB
    const int tid = threadIdx.x;
    const int n0 = blockIdx.x << BSH;
    const int nn = min(256, NN - n0);
    const int R0 = offs[n0];
    const int R1 = offs[min(n0 + 256, NN)];
    const int cnt = R1 - R0;
    if (tid < nn) cur[tid] = offs[n0 + tid] - R0;
    __syncthreads();
    if (cnt <= CAPB) {
        for (int i = tid; i < cnt; i += 256) {
            const uint_t r = grec[R0 + i];
            const int p = atomicAdd(&cur[r >> 17], 1);
            sbuf[p] = r;
        }
        __syncthreads();
        for (int i = tid; i < cnt; i += 256) {
            const uint_t r = sbuf[i];
            const int s = (int)(r & 0x1FFFF);
            const int n = n0 + (int)(r >> 17);
            const float4 a = *(const float4*)(s_src + (size_t)s * 4);
            const float4 b = *(const float4*)(s_tgt + (size_t)n * 4);
            const float sc0 = a.x + b.x, sc1 = a.y + b.y, sc2 = a.z + b.z, sc3 = a.w + b.w;
            sorted_src[R0 + i] = s;
            wts[0 * (size_t)EE + R0 + i] = __expf(-(sc0 > 0.f ? sc0 : 0.2f * sc0));
            wts[1 * (size_t)EE + R0 + i] = __expf(-(sc1 > 0.f ? sc1 : 0.2f * sc1));
            wts[2 * (size_t)EE + R0 + i] = __expf(-(sc2 > 0.f ? sc2 : 0.2f * sc2));
            wts[3 * (size_t)EE + R0 + i] = __expf(-(sc3 > 0.f ? sc3 : 0.2f * sc3));
        }
    } else {   // statistically unreachable fallback (>= 64 sigma)
        for (int i = tid; i < cnt; i += 256) {
            const uint_t r = grec[R0 + i];
            const int p = atomicAdd(&cur[r >> 17], 1);
            const int s = (int)(r & 0x1FFFF);
            const int n = n0 + (int)(r >> 17);
            const float4 a = *(const float4*)(s_src + (size_t)s * 4);
            const float4 b = *(const float4*)(s_tgt + (size_t)n * 4);
            const float sc0 = a.x + b.x, sc1 = a.y + b.y, sc2 = a.z + b.z, sc3 = a.w + b.w;
            sorted_src[R0 + p] = s;
            wts[0 * (size_t)EE + R0 + p] = __expf(-(sc0 > 0.f ? sc0 : 0.2f * sc0));
            wts[1 * (size_t)EE + R0 + p] = __expf(-(sc1 > 0.f ? sc1 : 0.2f * sc1));
            wts[2 * (size_t)EE + R0 + p] = __expf(-(sc2 > 0.f ? sc2 : 0.2f * sc2));
            wts[3 * (size_t)EE + R0 + p] = __expf(-(sc3 > 0.f ? sc3 : 0.2f * sc3));
        }
    }
}

// ---------------- gather: one wave per node, pure load+FMA inner loop
__global__ __launch_bounds__(256) void gather_k(const int* __restrict__ offs,
                                                const int* __restrict__ sorted_src,
                                                const float* __restrict__ wts,
                                                const ushort_t* __restrict__ hb,
                                                const float* __restrict__ bias,
                                                float* __restrict__ out) {
    const int n = blockIdx.x * 4 + (threadIdx.x >> 6);
    const int l = threadIdx.x & 63;
    const int c0 = l * 2;              // two channels per lane (same head)
    const int hd = l >> 4;
    const int p0 = offs[n], p1 = offs[n + 1];
    const float* wp = wts + (size_t)hd * EE;
    float ax = 0.f, ay = 0.f, wsum = 0.f;
    int p = p0;
    // peel to 16B alignment for uint4/float4 loads
    const int pre = min((4 - (p0 & 3)) & 3, p1 - p0);
    for (int q = 0; q < pre; ++q, ++p) {
        const int s0 = sorted_src[p];
        const float w0 = wp[p];
        const uint_t v0 = *(const uint_t*)(hb + (size_t)s0 * HO + c0);
        ax = fmaf(w0, bfl(v0), ax); ay = fmaf(w0, bfh(v0), ay);
        wsum += w0;
    }
    for (; p + 3 < p1; p += 4) {
        const uint4 s4 = *(const uint4*)(sorted_src + p);
        const float4 wv = *(const float4*)(wp + p);
        const uint_t v0 = *(const uint_t*)(hb + (size_t)s4.x * HO + c0);
        const uint_t v1 = *(const uint_t*)(hb + (size_t)s4.y * HO + c0);
        const uint_t v2 = *(const uint_t*)(hb + (size_t)s4.z * HO + c0);
        const uint_t v3 = *(const uint_t*)(hb + (size_t)s4.w * HO + c0);
        ax = fmaf(wv.x, bfl(v0), ax); ay = fmaf(wv.x, bfh(v0), ay);
        ax = fmaf(wv.y, bfl(v1), ax); ay = fmaf(wv.y, bfh(v1), ay);
        ax = fmaf(wv.z, bfl(v2), ax); ay = fmaf(wv.z, bfh(v2), ay);
        ax = fmaf(wv.w, bfl(v3), ax); ay = fmaf(wv.w, bfh(v3), ay);
        wsum += (wv.x + wv.y) + (wv.z + wv.w);
    }
    for (; p < p1; ++p) {
        const int s0 = sorted_src[p];
        const float w0 = wp[p];
        const uint_t v0 = *(const uint_t*)(hb + (size_t)s0 * HO + c0);
        ax = fmaf(w0, bfl(v0), ax); ay = fmaf(w0, bfh(v0), ay);
        wsum += w0;
    }
    const float inv = 1.f / fmaxf(wsum, 1e-10f);
    float2 o;
    o.x = ax * inv + bias[c0];
    o.y = ay * inv + bias[c0 + 1];
    *(float2*)(out + (size_t)n * HO + c0) = o;
}

extern "C" void kernel_launch(void* const* d_in, const int* in_sizes, int n_in,
                              void* d_out, int out_size, void* d_ws, size_t ws_size,
                              hipStream_t stream) {
    const float* x    = (const float*)d_in[0];
    const int*   ei   = (const int*)d_in[1];
    const float* W    = (const float*)d_in[2];
    const float* att  = (const float*)d_in[3];
    const float* bias = (const float*)d_in[4];
    float* out = (float*)d_out;

    char* ws = (char*)d_ws;
    const size_t HB_B  = (size_t)NN * HO * 2;        // 25.6 MB (bf16 h)
    const size_t SS_B  = (size_t)EE * 4;             // 6.4 MB
    const size_t GR_B  = (size_t)EE * 4;             // 6.4 MB (packed records)
    const size_t WT_B  = (size_t)EE * 4 * HEADS;     // 25.6 MB (planar wts)
    const size_t S_B   = (size_t)NN * HEADS * 4;     // 1.6 MB
    const size_t DEG_B = (size_t)NN * 4;             // 400 KB
    const size_t OFF_B = ((size_t)(NN + 1) * 4 + 15) & ~15ull;
    const size_t BS_B  = 256 * 4;
    const size_t GC_B  = ((size_t)NBUCK * 4 + 15) & ~15ull;

    size_t o = 0;
    ushort_t* hb         = (ushort_t*)(ws + o); o += HB_B;
    int*      sorted_src = (int*)(ws + o); o += SS_B;
    uint_t*   grec       = (uint_t*)(ws + o); o += GR_B;
    float*    wts        = (float*)(ws + o); o += WT_B;
    float*    ssrc       = (float*)(ws + o); o += S_B;
    float*    stgt       = (float*)(ws + o); o += S_B;
    int*      deg        = (int*)(ws + o); o += DEG_B;
    int*      offs       = (int*)(ws + o); o += OFF_B;
    int*      gcur       = (int*)(ws + o); o += GC_B;
    int*      blockSums  = (int*)(ws + o); o += BS_B;
    int*      blockOffs  = (int*)(ws + o); o += BS_B;

    hipMemsetAsync(deg, 0, DEG_B, stream);

    gemm_h<<<NN / 32, 256, 0, stream>>>(x, W, att, hb, ssrc, stgt);       // 3125 blocks
    hist_k<<<(EE + 255) / 256, 256, 0, stream>>>(ei, deg);                // 6250 blocks
    blocksum_k<<<SCAN_BLOCKS, 256, 0, stream>>>(deg, blockSums);
    scansums_k<<<1, 256, 0, stream>>>(blockSums, blockOffs, offs);
    scanapply_k<<<SCAN_BLOCKS, 256, 0, stream>>>(deg, blockOffs, offs, gcur);
    bucketA_k<<<ABLK, 256, 0, stream>>>(ei, gcur, grec);                  // 196 blocks
    bucketB_k<<<NBUCK, 256, 0, stream>>>(offs, grec, ssrc, stgt,
                                         sorted_src, wts);                // 391 blocks
    gather_k<<<NN / 4, 256, 0, stream>>>(offs, sorted_src, wts,
                                         hb, bias, out);                  // 25000 blocks
}